// Round 10
// baseline (546.291 us; speedup 1.0000x reference)
//
#include <hip/hip_runtime.h>
#include <cstdint>
#include <cstddef>

#define BATCH 8
#define CIN 64
#define HIN 70
#define HOUT 64
#define NPIX 4096
#define MPIX 1024

typedef __attribute__((ext_vector_type(8))) short short8;
typedef __attribute__((ext_vector_type(4))) float f32x4;
typedef __attribute__((ext_vector_type(4))) unsigned int uint4v;

__device__ __forceinline__ unsigned short f2bf_rne(float f) {
  unsigned int u = __builtin_bit_cast(unsigned int, f);
  unsigned int r = (u + 0x7FFFu + ((u >> 16) & 1u)) >> 16;
  return (unsigned short)r;
}

__device__ __forceinline__ unsigned int rot16(unsigned int u) {
  return (u >> 16) | (u << 16);
}

// ---------------------------------------------------------------------------
// prep_x: x [8][64][70][70] f32 -> xTi [8][70][70][128] ushort (hi/lo pairs)
// ---------------------------------------------------------------------------
__global__ __launch_bounds__(256) void prep_x(const float* __restrict__ x,
                                              unsigned int* __restrict__ xTi) {
  __shared__ float tile[64][71];
  const int blk = blockIdx.x;  // 0..559
  const int b = blk / 70;
  const int r = blk - b * 70;
  const int t = threadIdx.x;
  for (int i = t; i < 64 * 70; i += 256) {
    int ci = i / 70;
    int c = i - ci * 70;
    tile[ci][c] = x[(((size_t)(b * 64 + ci)) * 70 + r) * 70 + c];
  }
  __syncthreads();
  for (int i = t; i < 70 * 64; i += 256) {
    int c = i >> 6;
    int ci = i & 63;
    float a = tile[ci][c];
    unsigned short hi = f2bf_rne(a);
    float hif = __builtin_bit_cast(float, ((unsigned int)hi) << 16);
    unsigned short lo = f2bf_rne(a - hif);
    xTi[(((size_t)(b * 70 + r)) * 70 + c) * 64 + ci] =
        (unsigned int)hi | (((unsigned int)lo) << 16);
  }
}

// ---------------------------------------------------------------------------
// prep_w: weights -> wTi [49 s][448 OC][64 dw] (hi/lo pairs) + biasPad fill.
// OC: 0..99 theta, 100..199 phi, 200..399 g, 400..447 zero-pad
// ---------------------------------------------------------------------------
__global__ __launch_bounds__(256) void prep_w(
    const float* __restrict__ tw, const float* __restrict__ pw,
    const float* __restrict__ gw,
    const float* __restrict__ tb, const float* __restrict__ pb,
    const float* __restrict__ gb,
    unsigned int* __restrict__ wTi, float* __restrict__ biasPad) {
  int gid = blockIdx.x * 256 + threadIdx.x;  // 49*448*64 = 1,404,928 dwords
  if (gid >= 49 * 448 * 64) return;
  if (gid < 448) {
    float bv = 0.0f;
    if (gid < 100) bv = tb[gid];
    else if (gid < 200) bv = pb[gid - 100];
    else if (gid < 400) bv = gb[gid - 200];
    biasPad[gid] = bv;
  }
  int ci = gid & 63;
  int OC = (gid >> 6) % 448;
  int s = gid / (448 * 64);
  float v = 0.0f;
  if (OC < 100) v = tw[((size_t)(OC * 64 + ci)) * 49 + s];
  else if (OC < 200) v = pw[((size_t)((OC - 100) * 64 + ci)) * 49 + s];
  else if (OC < 400) v = gw[((size_t)((OC - 200) * 64 + ci)) * 49 + s];
  unsigned short hi = f2bf_rne(v);
  float hif = __builtin_bit_cast(float, ((unsigned int)hi) << 16);
  unsigned short lo = f2bf_rne(v - hif);
  wTi[gid] = (unsigned int)hi | (((unsigned int)lo) << 16);
}

// ---------------------------------------------------------------------------
// convmfma v5: dual-bf16 implicit-GEMM conv, 512-thread / 8-row blocks.
//  - grid (64, 7): x = b*8+ptile (8 output rows), y = 64-oc tile of 448
//  - 8 waves; wave wv = output row; acc[4 ocfrag][4 pxfrag]
//  - X [14][70][64B] swizzled (62720 B); W single-slice LDS dbuf 2x4096 B
//    (r7-proven scheme, staged by threads t<256), 1 barrier/slice
//  - LDS total 70,912 B -> solid 2 blocks/CU (16 waves) vs r9's 79,360
//  - epilogue: theta dual-bf16 + thd pad-zero (dw 100..127); phi/g 2x2
//    maxpool + phd pad-zero + gP pad rows (ch<408, vfinal==0 there)
// ---------------------------------------------------------------------------
__global__ __launch_bounds__(512, 2) void convmfma_kernel(
    const unsigned short* __restrict__ xTi,  // [8][70][70][128]
    const unsigned short* __restrict__ wTi,  // [49][448][128]
    const float* __restrict__ biasPad,       // [448]
    unsigned int* __restrict__ thd_dw,       // [8][4096][128]
    unsigned int* __restrict__ phd_dw,       // [8][1024][128]
    unsigned short* __restrict__ gP) {       // [8][208][1024]
  __shared__ __align__(16) char smem[62720 + 8192];
  const int LDSW = 62720;

  const int gx = blockIdx.x;      // 0..63
  const int b = gx >> 3;
  const int ptile = gx & 7;
  const int oy0 = ptile * 8;
  const int oc0 = blockIdx.y << 6;  // 0..384

  const int t = threadIdx.x;      // 0..511
  const int wv = t >> 6;          // 0..7 : output row within block
  const int l = t & 63;
  const int lm = l & 15;
  const int lg = l >> 4;
  const int py = oy0 + wv;

  // W staging ids (threads t<256 only): oc row, 16B quarter
  const int oc_t = (t >> 2) & 63;
  const int q = t & 3;
  const int wdstOff = (oc_t << 6) + ((q << 4) ^ (((oc_t >> 1) & 3) << 4));
  const int keyA = ((lm >> 1) & 3) << 4;
  const int laneA = (lm << 6) + ((lg << 4) ^ keyA);

  f32x4 acc[4][4];  // [oc j][px f]
#pragma unroll
  for (int j = 0; j < 4; ++j)
#pragma unroll
    for (int f = 0; f < 4; ++f) acc[j][f] = (f32x4)0.0f;

  for (int chunk = 0; chunk < 4; ++chunk) {
    // (final barrier of previous chunk drained all reads)
    // ---- stage X chunk: [14][70] lines of 64B, 16B-quarter XOR swizzle
    for (int i = t; i < 3920; i += 512) {
      int idx70 = i >> 2;
      int s16 = i & 3;
      int rr = idx70 / 70;
      int cc = idx70 - rr * 70;
      const unsigned short* src =
          xTi + ((((size_t)(b * 70 + oy0 + rr)) * 70 + cc) << 7) +
          (chunk << 5) + (s16 << 3);
      short8 v = *(const short8*)src;
      int dst = (idx70 << 6) + ((s16 << 4) ^ (((cc >> 1) & 3) << 4));
      *(short8*)(smem + dst) = v;
    }
    // ---- W pipeline prologue: slot0 <- W(0); wreg <- W(1)   (t<256 only)
    const unsigned short* wsrcBase =
        wTi + ((size_t)(oc0 + oc_t) << 7) + (chunk << 5) + (q << 3);
    short8 wreg = short8{};
    if (t < 256) {
      wreg = *(const short8*)wsrcBase;            // W(0)
      *(short8*)(smem + LDSW + wdstOff) = wreg;   // slot 0
      wreg = *(const short8*)(wsrcBase + 57344);  // W(1)  (448*128 us/slice)
    }
    __syncthreads();  // X staged + slot0 visible

    for (int ky = 0; ky < 7; ++ky) {
      for (int kx = 0; kx < 7; ++kx) {
        const int s = ky * 7 + kx;
        // ---- A frags (weights) from slot (s&1) + pair-swapped copies
        const char* wb = smem + LDSW + ((s & 1) << 12) + laneA;
        short8 aW[4], aS[4];
#pragma unroll
        for (int j = 0; j < 4; ++j) {
          aW[j] = *(const short8*)(wb + j * 1024);
          uint4v u = __builtin_bit_cast(uint4v, aW[j]);
          u.x = rot16(u.x); u.y = rot16(u.y);
          u.z = rot16(u.z); u.w = rot16(u.w);
          aS[j] = __builtin_bit_cast(short8, u);
        }
        // ---- B frags (X pixels) + MFMA
        const int klx = kx + lm;
        const int key = ((klx >> 1) & 3) << 4;
        const char* bbase =
            smem + ((wv + ky) * 70 + klx) * 64 + ((lg << 4) ^ key);
#pragma unroll
        for (int f = 0; f < 4; ++f) {
          short8 bf = *(const short8*)(bbase + f * 1024);
#pragma unroll
          for (int j = 0; j < 4; ++j) {
            acc[j][f] = __builtin_amdgcn_mfma_f32_16x16x32_bf16(
                aW[j], bf, acc[j][f], 0, 0, 0);
            acc[j][f] = __builtin_amdgcn_mfma_f32_16x16x32_bf16(
                aS[j], bf, acc[j][f], 0, 0, 0);
          }
        }
        // ---- W pipeline: write W(s+1) into other slot; prefetch W(s+2)
        if (t < 256 && s < 48) {
          *(short8*)(smem + LDSW + (((s + 1) & 1) << 12) + wdstOff) = wreg;
          if (s < 47)
            wreg = *(const short8*)(wsrcBase + (size_t)(s + 2) * 57344);
        }
        __syncthreads();  // one barrier per slice
      }
    }
  }

  // ---- epilogue ----
  float bia[4][4];
#pragma unroll
  for (int j = 0; j < 4; ++j)
#pragma unroll
    for (int r = 0; r < 4; ++r) bia[j][r] = biasPad[oc0 + j * 16 + lg * 4 + r];

  // theta full-res dual-bf16 + thd channel-pad zeros (dw 100..127)
#pragma unroll
  for (int j = 0; j < 4; ++j) {
#pragma unroll
    for (int f = 0; f < 4; ++f) {
#pragma unroll
      for (int r = 0; r < 4; ++r) {
        int ch = oc0 + j * 16 + lg * 4 + r;
        int n = py * 64 + f * 16 + lm;
        if (ch < 100) {
          float v = acc[j][f][r] + bia[j][r];
          unsigned short hi = f2bf_rne(v);
          float hif = __builtin_bit_cast(float, ((unsigned int)hi) << 16);
          unsigned short lo = f2bf_rne(v - hif);
          thd_dw[(((size_t)(b << 12) + n) << 7) + ch] =
              (unsigned int)hi | (((unsigned int)lo) << 16);
        } else if (ch < 128) {
          thd_dw[(((size_t)(b << 12) + n) << 7) + ch] = 0u;  // K-pad zero
        }
      }
    }
  }

  __syncthreads();  // all waves done with smem compute reads
  float* scratch = (float*)smem;  // [4][64*33] floats (odd-row stash)

#pragma unroll
  for (int j = 0; j < 4; ++j) {
#pragma unroll
    for (int f = 0; f < 4; ++f) {
#pragma unroll
      for (int r = 0; r < 4; ++r) {
        float v = acc[j][f][r] + bia[j][r];
        float vn = fmaxf(v, __shfl_xor(v, 1));
        acc[j][f][r] = vn;  // keep for even waves
        if ((wv & 1) && !(lm & 1)) {
          int ch_local = j * 16 + lg * 4 + r;
          int mcol = f * 8 + (lm >> 1);
          scratch[(wv >> 1) * 2112 + ch_local * 33 + mcol] = vn;
        }
      }
    }
  }
  __syncthreads();

  if (!(wv & 1)) {
#pragma unroll
    for (int j = 0; j < 4; ++j) {
#pragma unroll
      for (int f = 0; f < 4; ++f) {
#pragma unroll
        for (int r = 0; r < 4; ++r) {
          if (!(lm & 1)) {
            int ch = oc0 + j * 16 + lg * 4 + r;
            int ch_local = j * 16 + lg * 4 + r;
            int mcol = f * 8 + (lm >> 1);
            float partner = scratch[(wv >> 1) * 2112 + ch_local * 33 + mcol];
            float vfinal = fmaxf(acc[j][f][r], partner);
            int m = (((oy0 >> 1) + (wv >> 1)) << 5) + mcol;
            if (ch >= 100 && ch < 200) {
              int c = ch - 100;
              unsigned short hi = f2bf_rne(vfinal);
              float hif = __builtin_bit_cast(float, ((unsigned int)hi) << 16);
              unsigned short lo = f2bf_rne(vfinal - hif);
              phd_dw[(((size_t)(b << 10) + m) << 7) + c] =
                  (unsigned int)hi | (((unsigned int)lo) << 16);
            } else if (ch >= 200 && ch < 408) {
              // gP real channels (cg<200) and pad rows 200..207 (vfinal==0
              // there: zero weights + zero bias)
              int cg = ch - 200;
              gP[((size_t)(b * 208 + cg) << 10) + m] = f2bf_rne(vfinal);
              if (ch < 228) {
                // phd channel-pad zero (c = 100..127)
                phd_dw[(((size_t)(b << 10) + m) << 7) + (ch - 100)] = 0u;
              }
            }
          }
        }
      }
    }
  }
}

// ---------------------------------------------------------------------------
// attn_mfma: flash-style attention (unchanged from round 5, verified)
// ---------------------------------------------------------------------------
__global__ __launch_bounds__(512, 2) void attn_mfma_kernel(
    const unsigned short* __restrict__ thd,  // [8][4096][256]
    const unsigned short* __restrict__ phd,  // [8][1024][256]
    const unsigned short* __restrict__ gP,   // [8][208][1024]
    float* __restrict__ out) {               // [8][200][4096]
  __shared__ __align__(16) char sm[140800];
  float* corrL = (float*)(sm + 131072);   // [64][32]
  float* statsL = (float*)(sm + 139264);  // [64][2][2]
  float* mFinL = (float*)(sm + 140288);   // [64]
  float* invL = (float*)(sm + 140544);    // [64]

  const int bx = blockIdx.x;
  const int b = bx >> 6;
  const int n0 = (bx & 63) << 6;
  const int t = threadIdx.x;
  const int w = t >> 6;
  const int l = t & 63;
  const int lm = l & 15;
  const int lg = l >> 4;
  const int rowTile = w & 3;
  const int mhalf = w >> 2;
  const int rowB = rowTile * 16 + lg * 4;

  short8 aA[8], aS[8];
  {
    const unsigned short* ap =
        thd + (((size_t)(b << 12) + n0 + rowTile * 16 + lm) << 8) + lg * 8;
#pragma unroll
    for (int kf = 0; kf < 8; ++kf) {
      short8 v = *(const short8*)(ap + kf * 32);
      aA[kf] = v;
      uint4v u = __builtin_bit_cast(uint4v, v);
      u.x = rot16(u.x); u.y = rot16(u.y); u.z = rot16(u.z); u.w = rot16(u.w);
      aS[kf] = __builtin_bit_cast(short8, u);
    }
  }

  float mRun[4], sRun[4];
#pragma unroll
  for (int r = 0; r < 4; ++r) { mRun[r] = -3.0e38f; sRun[r] = 0.0f; }

  for (int step = 0; step < 16; ++step) {
    const int m0 = mhalf * 512 + step * 32;
    f32x4 ac0 = (f32x4)0.f, ac1 = (f32x4)0.f;
    const unsigned short* bp0 =
        phd + (((size_t)(b << 10) + m0 + lm) << 8) + lg * 8;
    const unsigned short* bp1 = bp0 + (16 << 8);
#pragma unroll
    for (int kf = 0; kf < 8; ++kf) {
      short8 bv0 = *(const short8*)(bp0 + kf * 32);
      short8 bv1 = *(const short8*)(bp1 + kf * 32);
      ac0 = __builtin_amdgcn_mfma_f32_16x16x32_bf16(aA[kf], bv0, ac0, 0, 0, 0);
      ac1 = __builtin_amdgcn_mfma_f32_16x16x32_bf16(aA[kf], bv1, ac1, 0, 0, 0);
      ac0 = __builtin_amdgcn_mfma_f32_16x16x32_bf16(aS[kf], bv0, ac0, 0, 0, 0);
      ac1 = __builtin_amdgcn_mfma_f32_16x16x32_bf16(aS[kf], bv1, ac1, 0, 0, 0);
    }
    float tmax[4], pv0[4], pv1[4], csum[4];
#pragma unroll
    for (int r = 0; r < 4; ++r) tmax[r] = fmaxf(ac0[r], ac1[r]);
#pragma unroll
    for (int s = 1; s < 16; s <<= 1)
#pragma unroll
      for (int r = 0; r < 4; ++r) tmax[r] = fmaxf(tmax[r], __shfl_xor(tmax[r], s));
#pragma unroll
    for (int r = 0; r < 4; ++r) {
      float mNew = fmaxf(mRun[r], tmax[r]);
      float scale = __expf(mRun[r] - mNew);
      pv0[r] = __expf(ac0[r] - mNew);
      pv1[r] = __expf(ac1[r] - mNew);
      csum[r] = pv0[r] + pv1[r];
      mRun[r] = mNew;
      sRun[r] *= scale;
    }
#pragma unroll
    for (int s = 1; s < 16; s <<= 1)
#pragma unroll
      for (int r = 0; r < 4; ++r) csum[r] += __shfl_xor(csum[r], s);
#pragma unroll
    for (int r = 0; r < 4; ++r) sRun[r] += csum[r];
#pragma unroll
    for (int r = 0; r < 4; ++r) {
      int row = rowB + r;
      int sw = ((row & 7) << 4);
      int byte0 = (row << 11) + ((((m0 + lm) << 1)) ^ sw);
      int byte1 = (row << 11) + ((((m0 + 16 + lm) << 1)) ^ sw);
      *(unsigned short*)(sm + byte0) = f2bf_rne(pv0[r]);
      *(unsigned short*)(sm + byte1) = f2bf_rne(pv1[r]);
    }
    if (lm == 0) {
      int chunkIdx = mhalf * 16 + step;
#pragma unroll
      for (int r = 0; r < 4; ++r) corrL[(rowB + r) * 32 + chunkIdx] = mRun[r];
    }
  }
  if (lm == 0) {
#pragma unroll
    for (int r = 0; r < 4; ++r) {
      statsL[((rowB + r) * 2 + mhalf) * 2 + 0] = mRun[r];
      statsL[((rowB + r) * 2 + mhalf) * 2 + 1] = sRun[r];
    }
  }
  __syncthreads();

  if (t < 64) {
    float m0v = statsL[(t * 2 + 0) * 2 + 0];
    float s0v = statsL[(t * 2 + 0) * 2 + 1];
    float m1v = statsL[(t * 2 + 1) * 2 + 0];
    float s1v = statsL[(t * 2 + 1) * 2 + 1];
    float mF = fmaxf(m0v, m1v);
    float sF = s0v * __expf(m0v - mF) + s1v * __expf(m1v - mF);
    mFinL[t] = mF;
    invL[t] = 1.0f / sF;
  }
  __syncthreads();

  {
    int idx = t * 4;
#pragma unroll
    for (int i = 0; i < 4; ++i) {
      int row = (idx + i) >> 5;
      corrL[idx + i] = __expf(corrL[idx + i] - mFinL[row]);
    }
  }
  __syncthreads();

  {
    int row = t >> 3;
    int mb = (t & 7) << 7;
    int sw = ((row & 7) << 4);
    for (int j = 0; j < 16; ++j) {
      int m = mb + j * 8;
      int byte = (row << 11) + (((m << 1)) ^ sw);
      float corr = corrL[row * 32 + (m >> 5)];
      short8 pv8 = *(short8*)(sm + byte);
      short8 ov;
#pragma unroll
      for (int e = 0; e < 8; ++e) {
        unsigned short us = (unsigned short)pv8[e];
        float f = __builtin_bit_cast(float, ((unsigned int)us) << 16);
        ov[e] = (short)f2bf_rne(f * corr);
      }
      *(short8*)(sm + byte) = ov;
    }
  }
  __syncthreads();

  const int nct = mhalf ? 6 : 7;
  const int ct0 = mhalf ? 7 : 0;
  f32x4 oacc[7];
#pragma unroll
  for (int i = 0; i < 7; ++i) oacc[i] = (f32x4)0.f;

  const int rowA = rowTile * 16 + lm;
  const int swA = ((rowA & 7) << 4);
  const int rowABase = (rowA << 11);

  for (int ks = 0; ks < 32; ++ks) {
    short8 ap = *(const short8*)(
        sm + rowABase + ((((ks * 32 + lg * 8) << 1)) ^ swA));
    const unsigned short* gbase =
        gP + ((size_t)(b * 208) << 10) + ks * 32 + lg * 8;
#pragma unroll
    for (int i = 0; i < 7; ++i) {
      if (i < nct) {
        int c = (ct0 + i) * 16 + lm;
        short8 gv = *(const short8*)(gbase + ((size_t)c << 10));
        oacc[i] = __builtin_amdgcn_mfma_f32_16x16x32_bf16(ap, gv, oacc[i], 0, 0, 0);
      }
    }
  }
  {
    float inv[4];
#pragma unroll
    for (int r = 0; r < 4; ++r) inv[r] = invL[rowB + r];
#pragma unroll
    for (int i = 0; i < 7; ++i) {
      if (i < nct) {
        int c = (ct0 + i) * 16 + lm;
        if (c < 200) {
          f32x4 v;
#pragma unroll
          for (int r = 0; r < 4; ++r) v[r] = oacc[i][r] * inv[r];
          *(f32x4*)(out + (((size_t)(b * 200 + c)) << 12) + n0 + rowB) = v;
        }
      }
    }
  }
}

// ---------------------------------------------------------------------------
extern "C" void kernel_launch(void* const* d_in, const int* in_sizes, int n_in,
                              void* d_out, int out_size, void* d_ws,
                              size_t ws_size, hipStream_t stream) {
  const float* x  = (const float*)d_in[0];
  const float* tw = (const float*)d_in[1];
  const float* tb = (const float*)d_in[2];
  const float* pw = (const float*)d_in[3];
  const float* pb = (const float*)d_in[4];
  const float* gw = (const float*)d_in[5];
  const float* gb = (const float*)d_in[6];
  float* out = (float*)d_out;

  unsigned short* ws_us = (unsigned short*)d_ws;
  unsigned short* thd = ws_us;               // 8*4096*256     = 8,388,608 us
  unsigned short* phd = ws_us + 8388608;     // 8*1024*256     = 2,097,152
  unsigned short* gP  = ws_us + 10485760;    // 8*208*1024     = 1,703,936
  unsigned short* xTi = ws_us + 12189696;    // 8*70*70*128    = 5,017,600
  unsigned short* wTi = ws_us + 17207296;    // 49*448*128     = 2,809,856
  float* biasPad = (float*)(ws_us + 20017152);  // 448 f (~40.1 MB total)

  prep_x<<<560, 256, 0, stream>>>(x, (unsigned int*)xTi);
  prep_w<<<5488, 256, 0, stream>>>(tw, pw, gw, tb, pb, gb,
                                   (unsigned int*)wTi, biasPad);

  convmfma_kernel<<<dim3(64, 7), 512, 0, stream>>>(
      xTi, wTi, biasPad, (unsigned int*)thd, (unsigned int*)phd, gP);
  attn_mfma_kernel<<<512, 512, 0, stream>>>(thd, phd, gP, out);
}

// Round 11
// 531.302 us; speedup vs baseline: 1.0282x; 1.0282x over previous
//
#include <hip/hip_runtime.h>
#include <cstdint>
#include <cstddef>

#define BATCH 8
#define CIN 64
#define HIN 70
#define HOUT 64
#define NPIX 4096
#define MPIX 1024

typedef __attribute__((ext_vector_type(8))) short short8;
typedef __attribute__((ext_vector_type(4))) float f32x4;
typedef __attribute__((ext_vector_type(4))) unsigned int uint4v;

__device__ __forceinline__ unsigned short f2bf_rne(float f) {
  unsigned int u = __builtin_bit_cast(unsigned int, f);
  unsigned int r = (u + 0x7FFFu + ((u >> 16) & 1u)) >> 16;
  return (unsigned short)r;
}

__device__ __forceinline__ unsigned int rot16(unsigned int u) {
  return (u >> 16) | (u << 16);
}

// ---------------------------------------------------------------------------
// prep_x: x [8][64][70][70] f32 -> xTi [8][70][70][128] ushort (hi/lo pairs)
// ---------------------------------------------------------------------------
__global__ __launch_bounds__(256) void prep_x(const float* __restrict__ x,
                                              unsigned int* __restrict__ xTi) {
  __shared__ float tile[64][71];
  const int blk = blockIdx.x;  // 0..559
  const int b = blk / 70;
  const int r = blk - b * 70;
  const int t = threadIdx.x;
  for (int i = t; i < 64 * 70; i += 256) {
    int ci = i / 70;
    int c = i - ci * 70;
    tile[ci][c] = x[(((size_t)(b * 64 + ci)) * 70 + r) * 70 + c];
  }
  __syncthreads();
  for (int i = t; i < 70 * 64; i += 256) {
    int c = i >> 6;
    int ci = i & 63;
    float a = tile[ci][c];
    unsigned short hi = f2bf_rne(a);
    float hif = __builtin_bit_cast(float, ((unsigned int)hi) << 16);
    unsigned short lo = f2bf_rne(a - hif);
    xTi[(((size_t)(b * 70 + r)) * 70 + c) * 64 + ci] =
        (unsigned int)hi | (((unsigned int)lo) << 16);
  }
}

// ---------------------------------------------------------------------------
// prep_w: weights -> wTi [49 s][448 OC][64 dw] (hi/lo pairs) + biasPad fill.
// OC: 0..99 theta, 100..199 phi, 200..399 g, 400..447 zero-pad
// ---------------------------------------------------------------------------
__global__ __launch_bounds__(256) void prep_w(
    const float* __restrict__ tw, const float* __restrict__ pw,
    const float* __restrict__ gw,
    const float* __restrict__ tb, const float* __restrict__ pb,
    const float* __restrict__ gb,
    unsigned int* __restrict__ wTi, float* __restrict__ biasPad) {
  int gid = blockIdx.x * 256 + threadIdx.x;  // 49*448*64 = 1,404,928 dwords
  if (gid >= 49 * 448 * 64) return;
  if (gid < 448) {
    float bv = 0.0f;
    if (gid < 100) bv = tb[gid];
    else if (gid < 200) bv = pb[gid - 100];
    else if (gid < 400) bv = gb[gid - 200];
    biasPad[gid] = bv;
  }
  int ci = gid & 63;
  int OC = (gid >> 6) % 448;
  int s = gid / (448 * 64);
  float v = 0.0f;
  if (OC < 100) v = tw[((size_t)(OC * 64 + ci)) * 49 + s];
  else if (OC < 200) v = pw[((size_t)((OC - 100) * 64 + ci)) * 49 + s];
  else if (OC < 400) v = gw[((size_t)((OC - 200) * 64 + ci)) * 49 + s];
  unsigned short hi = f2bf_rne(v);
  float hif = __builtin_bit_cast(float, ((unsigned int)hi) << 16);
  unsigned short lo = f2bf_rne(v - hif);
  wTi[gid] = (unsigned int)hi | (((unsigned int)lo) << 16);
}

// ---------------------------------------------------------------------------
// convmfma (r9 K-loop, verified fastest @295us + r10 inline-pad epilogue):
// 512-thread / 8-row blocks, pair-slot W staging, 1 barrier per 2 slices.
// ---------------------------------------------------------------------------
__global__ __launch_bounds__(512, 2) void convmfma_kernel(
    const unsigned short* __restrict__ xTi,  // [8][70][70][128]
    const unsigned short* __restrict__ wTi,  // [49][448][128]
    const float* __restrict__ biasPad,       // [448]
    unsigned int* __restrict__ thd_dw,       // [8][4096][128]
    unsigned int* __restrict__ phd_dw,       // [8][1024][128]
    unsigned short* __restrict__ gP) {       // [8][208][1024]
  __shared__ __align__(16) char smem[62720 + 16384];
  const int LDSW = 62720;

  const int gx = blockIdx.x;      // 0..63
  const int b = gx >> 3;
  const int ptile = gx & 7;
  const int oy0 = ptile * 8;
  const int oc0 = blockIdx.y << 6;  // 0..384

  const int t = threadIdx.x;      // 0..511
  const int wv = t >> 6;          // 0..7 : output row within block
  const int l = t & 63;
  const int lm = l & 15;
  const int lg = l >> 4;
  const int py = oy0 + wv;

  // W staging ids: sub-slice (0/1 within pair), oc row, 16B quarter
  const int sub = t >> 8;         // 0..1
  const int oc_t = (t >> 2) & 63; // 0..63
  const int q = t & 3;
  const int wdstOff =
      sub * 4096 + (oc_t << 6) + ((q << 4) ^ (((oc_t >> 1) & 3) << 4));
  const int keyA = ((lm >> 1) & 3) << 4;
  const int laneA = (lm << 6) + ((lg << 4) ^ keyA);

  f32x4 acc[4][4];  // [oc j][px f]
#pragma unroll
  for (int j = 0; j < 4; ++j)
#pragma unroll
    for (int f = 0; f < 4; ++f) acc[j][f] = (f32x4)0.0f;

  for (int chunk = 0; chunk < 4; ++chunk) {
    // (trailing barrier of previous chunk's last pair drained all reads)
    // ---- stage X chunk: [14][70] lines of 64B, 16B-quarter XOR swizzle
    for (int i = t; i < 3920; i += 512) {
      int idx70 = i >> 2;
      int s16 = i & 3;
      int rr = idx70 / 70;
      int cc = idx70 - rr * 70;
      const unsigned short* src =
          xTi + ((((size_t)(b * 70 + oy0 + rr)) * 70 + cc) << 7) +
          (chunk << 5) + (s16 << 3);
      short8 v = *(const short8*)src;
      int dst = (idx70 << 6) + ((s16 << 4) ^ (((cc >> 1) & 3) << 4));
      *(short8*)(smem + dst) = v;
    }
    // ---- W pipeline prologue: slot0 <- pair0; wreg <- pair1
    const unsigned short* wsrcBase =
        wTi + ((size_t)(oc0 + oc_t) << 7) + (chunk << 5) + (q << 3);
    short8 wreg = *(const short8*)(wsrcBase + (size_t)sub * 57344);  // pair 0
    *(short8*)(smem + LDSW + wdstOff) = wreg;                        // slot 0
    wreg = *(const short8*)(wsrcBase + (size_t)(2 + sub) * 57344);   // pair 1
    __syncthreads();  // X staged + slot0 visible

    for (int p = 0; p < 25; ++p) {
      const char* slotBase = smem + LDSW + ((p & 1) << 13);
#pragma unroll
      for (int halfs = 0; halfs < 2; ++halfs) {
        const int s = 2 * p + halfs;
        if (s <= 48) {
          const int ky = s / 7;
          const int kx = s - ky * 7;
          // ---- A frags (weights) + pair-swapped copies
          const char* wb = slotBase + (halfs << 12) + laneA;
          short8 aW[4], aS[4];
#pragma unroll
          for (int j = 0; j < 4; ++j) {
            aW[j] = *(const short8*)(wb + j * 1024);
            uint4v u = __builtin_bit_cast(uint4v, aW[j]);
            u.x = rot16(u.x); u.y = rot16(u.y);
            u.z = rot16(u.z); u.w = rot16(u.w);
            aS[j] = __builtin_bit_cast(short8, u);
          }
          // ---- B frags (X pixels) + MFMA
          const int klx = kx + lm;
          const int key = ((klx >> 1) & 3) << 4;
          const char* bbase =
              smem + ((wv + ky) * 70 + klx) * 64 + ((lg << 4) ^ key);
#pragma unroll
          for (int f = 0; f < 4; ++f) {
            short8 bf = *(const short8*)(bbase + f * 1024);
#pragma unroll
            for (int j = 0; j < 4; ++j) {
              acc[j][f] = __builtin_amdgcn_mfma_f32_16x16x32_bf16(
                  aW[j], bf, acc[j][f], 0, 0, 0);
              acc[j][f] = __builtin_amdgcn_mfma_f32_16x16x32_bf16(
                  aS[j], bf, acc[j][f], 0, 0, 0);
            }
          }
        }
      }
      // ---- W pipeline: write pair p+1 into other slot; prefetch pair p+2
      if (p < 24) {
        *(short8*)(smem + LDSW + (((p + 1) & 1) << 13) + wdstOff) = wreg;
        if (p < 23) {
          int snext = 2 * (p + 2) + sub;
          if (snext > 48) snext = 48;  // clamp (pair 24 tail)
          wreg = *(const short8*)(wsrcBase + (size_t)snext * 57344);
        }
      }
      __syncthreads();  // one barrier per PAIR of slices
    }
  }

  // ---- epilogue (r10-verified: inline pads) ----
  float bia[4][4];
#pragma unroll
  for (int j = 0; j < 4; ++j)
#pragma unroll
    for (int r = 0; r < 4; ++r) bia[j][r] = biasPad[oc0 + j * 16 + lg * 4 + r];

  // theta full-res dual-bf16 + thd channel-pad zeros (dw 100..127)
#pragma unroll
  for (int j = 0; j < 4; ++j) {
#pragma unroll
    for (int f = 0; f < 4; ++f) {
#pragma unroll
      for (int r = 0; r < 4; ++r) {
        int ch = oc0 + j * 16 + lg * 4 + r;
        int n = py * 64 + f * 16 + lm;
        if (ch < 100) {
          float v = acc[j][f][r] + bia[j][r];
          unsigned short hi = f2bf_rne(v);
          float hif = __builtin_bit_cast(float, ((unsigned int)hi) << 16);
          unsigned short lo = f2bf_rne(v - hif);
          thd_dw[(((size_t)(b << 12) + n) << 7) + ch] =
              (unsigned int)hi | (((unsigned int)lo) << 16);
        } else if (ch < 128) {
          thd_dw[(((size_t)(b << 12) + n) << 7) + ch] = 0u;  // K-pad zero
        }
      }
    }
  }

  __syncthreads();  // all waves done with smem compute reads
  float* scratch = (float*)smem;  // [4][64*33] floats (odd-row stash)

#pragma unroll
  for (int j = 0; j < 4; ++j) {
#pragma unroll
    for (int f = 0; f < 4; ++f) {
#pragma unroll
      for (int r = 0; r < 4; ++r) {
        float v = acc[j][f][r] + bia[j][r];
        float vn = fmaxf(v, __shfl_xor(v, 1));
        acc[j][f][r] = vn;  // keep for even waves
        if ((wv & 1) && !(lm & 1)) {
          int ch_local = j * 16 + lg * 4 + r;
          int mcol = f * 8 + (lm >> 1);
          scratch[(wv >> 1) * 2112 + ch_local * 33 + mcol] = vn;
        }
      }
    }
  }
  __syncthreads();

  if (!(wv & 1)) {
#pragma unroll
    for (int j = 0; j < 4; ++j) {
#pragma unroll
      for (int f = 0; f < 4; ++f) {
#pragma unroll
        for (int r = 0; r < 4; ++r) {
          if (!(lm & 1)) {
            int ch = oc0 + j * 16 + lg * 4 + r;
            int ch_local = j * 16 + lg * 4 + r;
            int mcol = f * 8 + (lm >> 1);
            float partner = scratch[(wv >> 1) * 2112 + ch_local * 33 + mcol];
            float vfinal = fmaxf(acc[j][f][r], partner);
            int m = (((oy0 >> 1) + (wv >> 1)) << 5) + mcol;
            if (ch >= 100 && ch < 200) {
              int c = ch - 100;
              unsigned short hi = f2bf_rne(vfinal);
              float hif = __builtin_bit_cast(float, ((unsigned int)hi) << 16);
              unsigned short lo = f2bf_rne(vfinal - hif);
              phd_dw[(((size_t)(b << 10) + m) << 7) + c] =
                  (unsigned int)hi | (((unsigned int)lo) << 16);
            } else if (ch >= 200 && ch < 408) {
              // gP real channels (cg<200) + pad rows 200..207 (vfinal==0)
              int cg = ch - 200;
              gP[((size_t)(b * 208 + cg) << 10) + m] = f2bf_rne(vfinal);
              if (ch < 228) {
                // phd channel-pad zero (c = 100..127)
                phd_dw[(((size_t)(b << 10) + m) << 7) + (ch - 100)] = 0u;
              }
            }
          }
        }
      }
    }
  }
}

// ---------------------------------------------------------------------------
// attn v2: 16-row blocks for occupancy. Block = (b, 16 n-rows), 256 thr,
// 4 waves = m-quarters (256 m each, 8 steps). LDS 35.5 KB -> 4 blocks/CU.
// Phase A: dual-bf16 QK^T + online softmax (per-wave quarter stats).
// Merge: 4-way stats -> mFin, inv. Rescale pass folds exp-corr AND 1/sum
// (P normalized in LDS). Phase C: P @ g^T, wave w owns c-tiles w, w+4, w+8
// (+12 for w=0); no inv needed at the end.
// ---------------------------------------------------------------------------
__global__ __launch_bounds__(256) void attn_kernel(
    const unsigned short* __restrict__ thd,  // [8][4096][256]
    const unsigned short* __restrict__ phd,  // [8][1024][256]
    const unsigned short* __restrict__ gP,   // [8][208][1024]
    float* __restrict__ out) {               // [8][200][4096]
  __shared__ __align__(16) char sm[32768 + 2048 + 512 + 64 + 64];
  float* corrL  = (float*)(sm + 32768);         // [16][32]
  float* statsL = (float*)(sm + 32768 + 2048);  // [16][4][2]
  float* mFinL  = (float*)(sm + 32768 + 2560);  // [16]
  float* invL   = (float*)(sm + 32768 + 2624);  // [16]

  const int bx = blockIdx.x;   // 0..2047
  const int b = bx >> 8;
  const int n0 = (bx & 255) << 4;
  const int t = threadIdx.x;
  const int w = t >> 6;        // m-quarter 0..3
  const int l = t & 63;
  const int lm = l & 15;
  const int lg = l >> 4;
  const int rowB = lg << 2;

  // theta A-frags (16 rows x K=256) + pair-swapped copy
  short8 aA[8], aS[8];
  {
    const unsigned short* ap =
        thd + (((size_t)(b << 12) + n0 + lm) << 8) + lg * 8;
#pragma unroll
    for (int kf = 0; kf < 8; ++kf) {
      short8 v = *(const short8*)(ap + kf * 32);
      aA[kf] = v;
      uint4v u = __builtin_bit_cast(uint4v, v);
      u.x = rot16(u.x); u.y = rot16(u.y); u.z = rot16(u.z); u.w = rot16(u.w);
      aS[kf] = __builtin_bit_cast(short8, u);
    }
  }

  float mRun[4], sRun[4];
#pragma unroll
  for (int r = 0; r < 4; ++r) { mRun[r] = -3.0e38f; sRun[r] = 0.0f; }

  // ---- Phase A over this wave's 256-m quarter (8 steps x 32 m)
  for (int step = 0; step < 8; ++step) {
    const int m0 = (w << 8) + (step << 5);
    f32x4 ac0 = (f32x4)0.f, ac1 = (f32x4)0.f;
    const unsigned short* bp0 =
        phd + (((size_t)(b << 10) + m0 + lm) << 8) + lg * 8;
    const unsigned short* bp1 = bp0 + (16 << 8);
#pragma unroll
    for (int kf = 0; kf < 8; ++kf) {
      short8 bv0 = *(const short8*)(bp0 + kf * 32);
      short8 bv1 = *(const short8*)(bp1 + kf * 32);
      ac0 = __builtin_amdgcn_mfma_f32_16x16x32_bf16(aA[kf], bv0, ac0, 0, 0, 0);
      ac1 = __builtin_amdgcn_mfma_f32_16x16x32_bf16(aA[kf], bv1, ac1, 0, 0, 0);
      ac0 = __builtin_amdgcn_mfma_f32_16x16x32_bf16(aS[kf], bv0, ac0, 0, 0, 0);
      ac1 = __builtin_amdgcn_mfma_f32_16x16x32_bf16(aS[kf], bv1, ac1, 0, 0, 0);
    }
    float tmax[4], pv0[4], pv1[4], csum[4];
#pragma unroll
    for (int r = 0; r < 4; ++r) tmax[r] = fmaxf(ac0[r], ac1[r]);
#pragma unroll
    for (int s = 1; s < 16; s <<= 1)
#pragma unroll
      for (int r = 0; r < 4; ++r) tmax[r] = fmaxf(tmax[r], __shfl_xor(tmax[r], s));
#pragma unroll
    for (int r = 0; r < 4; ++r) {
      float mNew = fmaxf(mRun[r], tmax[r]);
      float scale = __expf(mRun[r] - mNew);
      pv0[r] = __expf(ac0[r] - mNew);
      pv1[r] = __expf(ac1[r] - mNew);
      csum[r] = pv0[r] + pv1[r];
      mRun[r] = mNew;
      sRun[r] *= scale;
    }
#pragma unroll
    for (int s = 1; s < 16; s <<= 1)
#pragma unroll
      for (int r = 0; r < 4; ++r) csum[r] += __shfl_xor(csum[r], s);
#pragma unroll
    for (int r = 0; r < 4; ++r) sRun[r] += csum[r];
    // store P (bf16, swizzled: XOR on the m-byte offset only)
#pragma unroll
    for (int r = 0; r < 4; ++r) {
      int row = rowB + r;
      int sw = ((row & 7) << 4);
      int byte0 = (row << 11) + ((((m0 + lm) << 1)) ^ sw);
      int byte1 = (row << 11) + ((((m0 + 16 + lm) << 1)) ^ sw);
      *(unsigned short*)(sm + byte0) = f2bf_rne(pv0[r]);
      *(unsigned short*)(sm + byte1) = f2bf_rne(pv1[r]);
    }
    if (lm == 0) {
      int chunkIdx = (w << 3) + step;
#pragma unroll
      for (int r = 0; r < 4; ++r) corrL[(rowB + r) * 32 + chunkIdx] = mRun[r];
    }
  }
  if (lm == 0) {
#pragma unroll
    for (int r = 0; r < 4; ++r) {
      statsL[((rowB + r) * 4 + w) * 2 + 0] = mRun[r];
      statsL[((rowB + r) * 4 + w) * 2 + 1] = sRun[r];
    }
  }
  __syncthreads();

  // ---- merge the 4 quarter stats per row
  if (t < 16) {
    float mF = -3.0e38f;
#pragma unroll
    for (int qq = 0; qq < 4; ++qq)
      mF = fmaxf(mF, statsL[(t * 4 + qq) * 2 + 0]);
    float sF = 0.0f;
#pragma unroll
    for (int qq = 0; qq < 4; ++qq)
      sF += statsL[(t * 4 + qq) * 2 + 1] *
            __expf(statsL[(t * 4 + qq) * 2 + 0] - mF);
    mFinL[t] = mF;
    invL[t] = 1.0f / sF;
  }
  __syncthreads();

  // ---- convert m_used -> correction factors (fold in 1/sum)
  {
    int idx = t * 2;
#pragma unroll
    for (int i = 0; i < 2; ++i) {
      int e = idx + i;
      int row = e >> 5;
      corrL[e] = __expf(corrL[e] - mFinL[row]) * invL[row];
    }
  }
  __syncthreads();

  // ---- rescale + normalize P in LDS (same swizzle as write)
  {
    int row = t >> 4;
    int mseg = (t & 15) << 6;
    int sw = ((row & 7) << 4);
    for (int j = 0; j < 8; ++j) {
      int m = mseg + (j << 3);
      int byte = (row << 11) + (((m << 1)) ^ sw);
      float corr = corrL[row * 32 + (m >> 5)];
      short8 pv8 = *(short8*)(sm + byte);
      short8 ov;
#pragma unroll
      for (int e = 0; e < 8; ++e) {
        unsigned short us = (unsigned short)pv8[e];
        float f = __builtin_bit_cast(float, ((unsigned int)us) << 16);
        ov[e] = (short)f2bf_rne(f * corr);
      }
      *(short8*)(sm + byte) = ov;
    }
  }
  __syncthreads();

  // ---- Phase C: out[n][c] = sum_m P[n][m] g[c][m]  (P already normalized)
  f32x4 oacc[4];
#pragma unroll
  for (int i = 0; i < 4; ++i) oacc[i] = (f32x4)0.f;

  const int swA = ((lm & 7) << 4);
  const int rowABase = (lm << 11);

  for (int ks = 0; ks < 32; ++ks) {
    short8 ap = *(const short8*)(
        sm + rowABase + ((((ks * 32 + lg * 8) << 1)) ^ swA));
    const unsigned short* gbase =
        gP + ((size_t)(b * 208) << 10) + ks * 32 + lg * 8;
#pragma unroll
    for (int i = 0; i < 4; ++i) {
      int ct = w + (i << 2);
      if (ct < 13) {
        int c = (ct << 4) + lm;
        short8 gv = *(const short8*)(gbase + ((size_t)c << 10));
        oacc[i] = __builtin_amdgcn_mfma_f32_16x16x32_bf16(ap, gv, oacc[i], 0, 0, 0);
      }
    }
  }
#pragma unroll
  for (int i = 0; i < 4; ++i) {
    int ct = w + (i << 2);
    if (ct < 13) {
      int c = (ct << 4) + lm;
      if (c < 200) {
        *(f32x4*)(out + (((size_t)(b * 200 + c)) << 12) + n0 + rowB) = oacc[i];
      }
    }
  }
}

// ---------------------------------------------------------------------------
extern "C" void kernel_launch(void* const* d_in, const int* in_sizes, int n_in,
                              void* d_out, int out_size, void* d_ws,
                              size_t ws_size, hipStream_t stream) {
  const float* x  = (const float*)d_in[0];
  const float* tw = (const float*)d_in[1];
  const float* tb = (const float*)d_in[2];
  const float* pw = (const float*)d_in[3];
  const float* pb = (const float*)d_in[4];
  const float* gw = (const float*)d_in[5];
  const float* gb = (const float*)d_in[6];
  float* out = (float*)d_out;

  unsigned short* ws_us = (unsigned short*)d_ws;
  unsigned short* thd = ws_us;               // 8*4096*256     = 8,388,608 us
  unsigned short* phd = ws_us + 8388608;     // 8*1024*256     = 2,097,152
  unsigned short* gP  = ws_us + 10485760;    // 8*208*1024     = 1,703,936
  unsigned short* xTi = ws_us + 12189696;    // 8*70*70*128    = 5,017,600
  unsigned short* wTi = ws_us + 17207296;    // 49*448*128     = 2,809,856
  float* biasPad = (float*)(ws_us + 20017152);  // 448 f (~40.1 MB total)

  prep_x<<<560, 256, 0, stream>>>(x, (unsigned int*)xTi);
  prep_w<<<5488, 256, 0, stream>>>(tw, pw, gw, tb, pb, gb,
                                   (unsigned int*)wTi, biasPad);

  convmfma_kernel<<<dim3(64, 7), 512, 0, stream>>>(
      xTi, wTi, biasPad, (unsigned int*)thd, (unsigned int*)phd, gP);
  attn_kernel<<<2048, 256, 0, stream>>>(thd, phd, gP, out);
}

// Round 12
// 502.581 us; speedup vs baseline: 1.0870x; 1.0571x over previous
//
#include <hip/hip_runtime.h>
#include <cstdint>
#include <cstddef>

#define BATCH 8
#define CIN 64
#define HIN 70
#define HOUT 64
#define NPIX 4096
#define MPIX 1024

typedef __attribute__((ext_vector_type(8))) short short8;
typedef __attribute__((ext_vector_type(4))) float f32x4;
typedef __attribute__((ext_vector_type(4))) unsigned int uint4v;

__device__ __forceinline__ unsigned short f2bf_rne(float f) {
  unsigned int u = __builtin_bit_cast(unsigned int, f);
  unsigned int r = (u + 0x7FFFu + ((u >> 16) & 1u)) >> 16;
  return (unsigned short)r;
}

__device__ __forceinline__ unsigned int rot16(unsigned int u) {
  return (u >> 16) | (u << 16);
}

// ---------------------------------------------------------------------------
// prep_x: x [8][64][70][70] f32 -> xTi [8][70][70][128] ushort (hi/lo pairs)
// ---------------------------------------------------------------------------
__global__ __launch_bounds__(256) void prep_x(const float* __restrict__ x,
                                              unsigned int* __restrict__ xTi) {
  __shared__ float tile[64][71];
  const int blk = blockIdx.x;  // 0..559
  const int b = blk / 70;
  const int r = blk - b * 70;
  const int t = threadIdx.x;
  for (int i = t; i < 64 * 70; i += 256) {
    int ci = i / 70;
    int c = i - ci * 70;
    tile[ci][c] = x[(((size_t)(b * 64 + ci)) * 70 + r) * 70 + c];
  }
  __syncthreads();
  for (int i = t; i < 70 * 64; i += 256) {
    int c = i >> 6;
    int ci = i & 63;
    float a = tile[ci][c];
    unsigned short hi = f2bf_rne(a);
    float hif = __builtin_bit_cast(float, ((unsigned int)hi) << 16);
    unsigned short lo = f2bf_rne(a - hif);
    xTi[(((size_t)(b * 70 + r)) * 70 + c) * 64 + ci] =
        (unsigned int)hi | (((unsigned int)lo) << 16);
  }
}

// ---------------------------------------------------------------------------
// prep_w: weights -> wTi [49 s][448 OC][64 dw] (hi/lo pairs) + biasPad fill.
// ---------------------------------------------------------------------------
__global__ __launch_bounds__(256) void prep_w(
    const float* __restrict__ tw, const float* __restrict__ pw,
    const float* __restrict__ gw,
    const float* __restrict__ tb, const float* __restrict__ pb,
    const float* __restrict__ gb,
    unsigned int* __restrict__ wTi, float* __restrict__ biasPad) {
  int gid = blockIdx.x * 256 + threadIdx.x;
  if (gid >= 49 * 448 * 64) return;
  if (gid < 448) {
    float bv = 0.0f;
    if (gid < 100) bv = tb[gid];
    else if (gid < 200) bv = pb[gid - 100];
    else if (gid < 400) bv = gb[gid - 200];
    biasPad[gid] = bv;
  }
  int ci = gid & 63;
  int OC = (gid >> 6) % 448;
  int s = gid / (448 * 64);
  float v = 0.0f;
  if (OC < 100) v = tw[((size_t)(OC * 64 + ci)) * 49 + s];
  else if (OC < 200) v = pw[((size_t)((OC - 100) * 64 + ci)) * 49 + s];
  else if (OC < 400) v = gw[((size_t)((OC - 200) * 64 + ci)) * 49 + s];
  unsigned short hi = f2bf_rne(v);
  float hif = __builtin_bit_cast(float, ((unsigned int)hi) << 16);
  unsigned short lo = f2bf_rne(v - hif);
  wTi[gid] = (unsigned int)hi | (((unsigned int)lo) << 16);
}

// ---------------------------------------------------------------------------
// convmfma (r9 K-loop + r10 inline-pad epilogue; unchanged from r11)
// ---------------------------------------------------------------------------
__global__ __launch_bounds__(512, 2) void convmfma_kernel(
    const unsigned short* __restrict__ xTi,  // [8][70][70][128]
    const unsigned short* __restrict__ wTi,  // [49][448][128]
    const float* __restrict__ biasPad,       // [448]
    unsigned int* __restrict__ thd_dw,       // [8][4096][128]
    unsigned int* __restrict__ phd_dw,       // [8][1024][128]
    unsigned short* __restrict__ gP) {       // [8][208][1024]
  __shared__ __align__(16) char smem[62720 + 16384];
  const int LDSW = 62720;

  const int gx = blockIdx.x;      // 0..63
  const int b = gx >> 3;
  const int ptile = gx & 7;
  const int oy0 = ptile * 8;
  const int oc0 = blockIdx.y << 6;  // 0..384

  const int t = threadIdx.x;      // 0..511
  const int wv = t >> 6;
  const int l = t & 63;
  const int lm = l & 15;
  const int lg = l >> 4;
  const int py = oy0 + wv;

  const int sub = t >> 8;
  const int oc_t = (t >> 2) & 63;
  const int q = t & 3;
  const int wdstOff =
      sub * 4096 + (oc_t << 6) + ((q << 4) ^ (((oc_t >> 1) & 3) << 4));
  const int keyA = ((lm >> 1) & 3) << 4;
  const int laneA = (lm << 6) + ((lg << 4) ^ keyA);

  f32x4 acc[4][4];
#pragma unroll
  for (int j = 0; j < 4; ++j)
#pragma unroll
    for (int f = 0; f < 4; ++f) acc[j][f] = (f32x4)0.0f;

  for (int chunk = 0; chunk < 4; ++chunk) {
    for (int i = t; i < 3920; i += 512) {
      int idx70 = i >> 2;
      int s16 = i & 3;
      int rr = idx70 / 70;
      int cc = idx70 - rr * 70;
      const unsigned short* src =
          xTi + ((((size_t)(b * 70 + oy0 + rr)) * 70 + cc) << 7) +
          (chunk << 5) + (s16 << 3);
      short8 v = *(const short8*)src;
      int dst = (idx70 << 6) + ((s16 << 4) ^ (((cc >> 1) & 3) << 4));
      *(short8*)(smem + dst) = v;
    }
    const unsigned short* wsrcBase =
        wTi + ((size_t)(oc0 + oc_t) << 7) + (chunk << 5) + (q << 3);
    short8 wreg = *(const short8*)(wsrcBase + (size_t)sub * 57344);
    *(short8*)(smem + LDSW + wdstOff) = wreg;
    wreg = *(const short8*)(wsrcBase + (size_t)(2 + sub) * 57344);
    __syncthreads();

    for (int p = 0; p < 25; ++p) {
      const char* slotBase = smem + LDSW + ((p & 1) << 13);
#pragma unroll
      for (int halfs = 0; halfs < 2; ++halfs) {
        const int s = 2 * p + halfs;
        if (s <= 48) {
          const int ky = s / 7;
          const int kx = s - ky * 7;
          const char* wb = slotBase + (halfs << 12) + laneA;
          short8 aW[4], aS[4];
#pragma unroll
          for (int j = 0; j < 4; ++j) {
            aW[j] = *(const short8*)(wb + j * 1024);
            uint4v u = __builtin_bit_cast(uint4v, aW[j]);
            u.x = rot16(u.x); u.y = rot16(u.y);
            u.z = rot16(u.z); u.w = rot16(u.w);
            aS[j] = __builtin_bit_cast(short8, u);
          }
          const int klx = kx + lm;
          const int key = ((klx >> 1) & 3) << 4;
          const char* bbase =
              smem + ((wv + ky) * 70 + klx) * 64 + ((lg << 4) ^ key);
#pragma unroll
          for (int f = 0; f < 4; ++f) {
            short8 bf = *(const short8*)(bbase + f * 1024);
#pragma unroll
            for (int j = 0; j < 4; ++j) {
              acc[j][f] = __builtin_amdgcn_mfma_f32_16x16x32_bf16(
                  aW[j], bf, acc[j][f], 0, 0, 0);
              acc[j][f] = __builtin_amdgcn_mfma_f32_16x16x32_bf16(
                  aS[j], bf, acc[j][f], 0, 0, 0);
            }
          }
        }
      }
      if (p < 24) {
        *(short8*)(smem + LDSW + (((p + 1) & 1) << 13) + wdstOff) = wreg;
        if (p < 23) {
          int snext = 2 * (p + 2) + sub;
          if (snext > 48) snext = 48;
          wreg = *(const short8*)(wsrcBase + (size_t)snext * 57344);
        }
      }
      __syncthreads();
    }
  }

  float bia[4][4];
#pragma unroll
  for (int j = 0; j < 4; ++j)
#pragma unroll
    for (int r = 0; r < 4; ++r) bia[j][r] = biasPad[oc0 + j * 16 + lg * 4 + r];

#pragma unroll
  for (int j = 0; j < 4; ++j) {
#pragma unroll
    for (int f = 0; f < 4; ++f) {
#pragma unroll
      for (int r = 0; r < 4; ++r) {
        int ch = oc0 + j * 16 + lg * 4 + r;
        int n = py * 64 + f * 16 + lm;
        if (ch < 100) {
          float v = acc[j][f][r] + bia[j][r];
          unsigned short hi = f2bf_rne(v);
          float hif = __builtin_bit_cast(float, ((unsigned int)hi) << 16);
          unsigned short lo = f2bf_rne(v - hif);
          thd_dw[(((size_t)(b << 12) + n) << 7) + ch] =
              (unsigned int)hi | (((unsigned int)lo) << 16);
        } else if (ch < 128) {
          thd_dw[(((size_t)(b << 12) + n) << 7) + ch] = 0u;
        }
      }
    }
  }

  __syncthreads();
  float* scratch = (float*)smem;

#pragma unroll
  for (int j = 0; j < 4; ++j) {
#pragma unroll
    for (int f = 0; f < 4; ++f) {
#pragma unroll
      for (int r = 0; r < 4; ++r) {
        float v = acc[j][f][r] + bia[j][r];
        float vn = fmaxf(v, __shfl_xor(v, 1));
        acc[j][f][r] = vn;
        if ((wv & 1) && !(lm & 1)) {
          int ch_local = j * 16 + lg * 4 + r;
          int mcol = f * 8 + (lm >> 1);
          scratch[(wv >> 1) * 2112 + ch_local * 33 + mcol] = vn;
        }
      }
    }
  }
  __syncthreads();

  if (!(wv & 1)) {
#pragma unroll
    for (int j = 0; j < 4; ++j) {
#pragma unroll
      for (int f = 0; f < 4; ++f) {
#pragma unroll
        for (int r = 0; r < 4; ++r) {
          if (!(lm & 1)) {
            int ch = oc0 + j * 16 + lg * 4 + r;
            int ch_local = j * 16 + lg * 4 + r;
            int mcol = f * 8 + (lm >> 1);
            float partner = scratch[(wv >> 1) * 2112 + ch_local * 33 + mcol];
            float vfinal = fmaxf(acc[j][f][r], partner);
            int m = (((oy0 >> 1) + (wv >> 1)) << 5) + mcol;
            if (ch >= 100 && ch < 200) {
              int c = ch - 100;
              unsigned short hi = f2bf_rne(vfinal);
              float hif = __builtin_bit_cast(float, ((unsigned int)hi) << 16);
              unsigned short lo = f2bf_rne(vfinal - hif);
              phd_dw[(((size_t)(b << 10) + m) << 7) + c] =
                  (unsigned int)hi | (((unsigned int)lo) << 16);
            } else if (ch >= 200 && ch < 408) {
              int cg = ch - 200;
              gP[((size_t)(b * 208 + cg) << 10) + m] = f2bf_rne(vfinal);
              if (ch < 228) {
                phd_dw[(((size_t)(b << 10) + m) << 7) + (ch - 100)] = 0u;
              }
            }
          }
        }
      }
    }
  }
}

// ---------------------------------------------------------------------------
// attn v3: swapped QK^T -> P register-resident (no LDS P buffer).
// Block = (b, 16 n-rows), 256 thr, 4 waves = m-quarters (8 steps x 32 m).
// Phase A: mfma(A=phi, B=theta) -> D[m][n], n on lane&15. Softmax over m:
//   local 8-max + 2 shfl_xor(16/32). P packed bf16 + 8-shfl lane permute
//   into phase-C A-frag layout (Pr[8][4] dwords).
// Merge 4-way stats; in-register rescale by exp-corr * 1/sum.
// Phase C: per wave, 13 c-tiles over its m-quarter from Pr regs; 4-round
// LDS reduce outAcc[16][212]; coalesced final write.
// ---------------------------------------------------------------------------
__global__ __launch_bounds__(256) void attn_kernel(
    const unsigned short* __restrict__ thd,  // [8][4096][256]
    const unsigned short* __restrict__ phd,  // [8][1024][256]
    const unsigned short* __restrict__ gP,   // [8][208][1024]
    float* __restrict__ out) {               // [8][200][4096]
  __shared__ __align__(16) float outAcc[16][212];  // padded vs 208
  __shared__ float corrL[16][33];                  // padded vs 32
  __shared__ float statsL[4][16][2];
  __shared__ float mFinL[16];
  __shared__ float invL[16];

  const int bx = blockIdx.x;   // 0..2047
  const int b = bx >> 8;
  const int n0 = (bx & 255) << 4;
  const int t = threadIdx.x;
  const int w = t >> 6;        // m-quarter 0..3
  const int l = t & 63;
  const int lm = l & 15;
  const int lg = l >> 4;

  // theta frags (B-operand: col n = n0+lm, k-slice lg) + pair-swapped copy
  short8 aA[8], aS[8];
  {
    const unsigned short* ap =
        thd + (((size_t)(b << 12) + n0 + lm) << 8) + lg * 8;
#pragma unroll
    for (int kf = 0; kf < 8; ++kf) {
      short8 v = *(const short8*)(ap + kf * 32);
      aA[kf] = v;
      uint4v u = __builtin_bit_cast(uint4v, v);
      u.x = rot16(u.x); u.y = rot16(u.y); u.z = rot16(u.z); u.w = rot16(u.w);
      aS[kf] = __builtin_bit_cast(short8, u);
    }
  }

  float mRun = -3.0e38f, sRun = 0.0f;
  unsigned int Pr[8][4];

  const int src1 = ((lg & 1) << 5) + lm;  // ((lg&1)*2)*16 + lm
  const int src2 = src1 + 16;
  const bool hi2 = (lg >> 1) != 0;

#pragma unroll
  for (int step = 0; step < 8; ++step) {
    const int m0 = (w << 8) + (step << 5);
    f32x4 ac0 = (f32x4)0.f, ac1 = (f32x4)0.f;
    const unsigned short* bp0 =
        phd + (((size_t)(b << 10) + m0 + lm) << 8) + lg * 8;
    const unsigned short* bp1 = bp0 + (16 << 8);
#pragma unroll
    for (int kf = 0; kf < 8; ++kf) {
      short8 av0 = *(const short8*)(bp0 + kf * 32);
      short8 av1 = *(const short8*)(bp1 + kf * 32);
      ac0 = __builtin_amdgcn_mfma_f32_16x16x32_bf16(av0, aA[kf], ac0, 0, 0, 0);
      ac1 = __builtin_amdgcn_mfma_f32_16x16x32_bf16(av1, aA[kf], ac1, 0, 0, 0);
      ac0 = __builtin_amdgcn_mfma_f32_16x16x32_bf16(av0, aS[kf], ac0, 0, 0, 0);
      ac1 = __builtin_amdgcn_mfma_f32_16x16x32_bf16(av1, aS[kf], ac1, 0, 0, 0);
    }
    // softmax over m-chunk (n fixed per lane); reduce over 4 lg-lanes
    float tm = fmaxf(fmaxf(fmaxf(ac0[0], ac0[1]), fmaxf(ac0[2], ac0[3])),
                     fmaxf(fmaxf(ac1[0], ac1[1]), fmaxf(ac1[2], ac1[3])));
    tm = fmaxf(tm, __shfl_xor(tm, 16));
    tm = fmaxf(tm, __shfl_xor(tm, 32));
    float mNew = fmaxf(mRun, tm);
    float scale = __expf(mRun - mNew);
    float p0 = __expf(ac0[0] - mNew), p1 = __expf(ac0[1] - mNew);
    float p2 = __expf(ac0[2] - mNew), p3 = __expf(ac0[3] - mNew);
    float q0 = __expf(ac1[0] - mNew), q1 = __expf(ac1[1] - mNew);
    float q2 = __expf(ac1[2] - mNew), q3 = __expf(ac1[3] - mNew);
    float cs = ((p0 + p1) + (p2 + p3)) + ((q0 + q1) + (q2 + q3));
    cs += __shfl_xor(cs, 16);
    cs += __shfl_xor(cs, 32);
    mRun = mNew;
    sRun = sRun * scale + cs;
    if (l < 16) corrL[lm][(w << 3) + step] = mRun;
    // pack to bf16 dwords
    unsigned int d0 = (unsigned int)f2bf_rne(p0) |
                      (((unsigned int)f2bf_rne(p1)) << 16);
    unsigned int d1 = (unsigned int)f2bf_rne(p2) |
                      (((unsigned int)f2bf_rne(p3)) << 16);
    unsigned int e0 = (unsigned int)f2bf_rne(q0) |
                      (((unsigned int)f2bf_rne(q1)) << 16);
    unsigned int e1 = (unsigned int)f2bf_rne(q2) |
                      (((unsigned int)f2bf_rne(q3)) << 16);
    // lane permute into A-frag layout: lane lg gets m = m0 + lg*8 + 0..7
    unsigned int A0 = (unsigned int)__shfl((int)d0, src1);
    unsigned int A1 = (unsigned int)__shfl((int)d1, src1);
    unsigned int B0 = (unsigned int)__shfl((int)d0, src2);
    unsigned int B1 = (unsigned int)__shfl((int)d1, src2);
    unsigned int C0 = (unsigned int)__shfl((int)e0, src1);
    unsigned int C1 = (unsigned int)__shfl((int)e1, src1);
    unsigned int D0 = (unsigned int)__shfl((int)e0, src2);
    unsigned int D1 = (unsigned int)__shfl((int)e1, src2);
    Pr[step][0] = hi2 ? C0 : A0;
    Pr[step][1] = hi2 ? C1 : A1;
    Pr[step][2] = hi2 ? D0 : B0;
    Pr[step][3] = hi2 ? D1 : B1;
  }
  if (l < 16) {
    statsL[w][lm][0] = mRun;
    statsL[w][lm][1] = sRun;
  }
  __syncthreads();

  // merge the 4 quarter stats per row
  if (t < 16) {
    float mF = -3.0e38f;
#pragma unroll
    for (int qq = 0; qq < 4; ++qq) mF = fmaxf(mF, statsL[qq][t][0]);
    float sF = 0.0f;
#pragma unroll
    for (int qq = 0; qq < 4; ++qq)
      sF += statsL[qq][t][1] * __expf(statsL[qq][t][0] - mF);
    mFinL[t] = mF;
    invL[t] = 1.0f / sF;
  }
  __syncthreads();

  // m_used -> correction factors, 1/sum folded in
  {
    int e = t * 2;
#pragma unroll
    for (int i = 0; i < 2; ++i) {
      int row = (e + i) >> 5;
      int col = (e + i) & 31;
      corrL[row][col] = __expf(corrL[row][col] - mFinL[row]) * invL[row];
    }
  }
  __syncthreads();

  // in-register rescale of P
#pragma unroll
  for (int s = 0; s < 8; ++s) {
    float corr = corrL[lm][(w << 3) + s];
#pragma unroll
    for (int j = 0; j < 4; ++j) {
      unsigned int u = Pr[s][j];
      float lo = __builtin_bit_cast(float, u << 16);
      float hi = __builtin_bit_cast(float, u & 0xffff0000u);
      Pr[s][j] = (unsigned int)f2bf_rne(lo * corr) |
                 (((unsigned int)f2bf_rne(hi * corr)) << 16);
    }
  }

  // Phase C: partial over this wave's m-quarter, all 13 c-tiles
  f32x4 oacc[13];
#pragma unroll
  for (int i = 0; i < 13; ++i) oacc[i] = (f32x4)0.f;

#pragma unroll
  for (int s = 0; s < 8; ++s) {
    uint4v pu;
    pu.x = Pr[s][0]; pu.y = Pr[s][1]; pu.z = Pr[s][2]; pu.w = Pr[s][3];
    short8 pf = __builtin_bit_cast(short8, pu);
    const unsigned short* gbase =
        gP + ((size_t)(b * 208) << 10) + (w << 8) + (s << 5) + lg * 8;
#pragma unroll
    for (int ct = 0; ct < 13; ++ct) {
      int c = (ct << 4) + lm;
      short8 gv = *(const short8*)(gbase + ((size_t)c << 10));
      oacc[ct] = __builtin_amdgcn_mfma_f32_16x16x32_bf16(pf, gv, oacc[ct], 0, 0, 0);
    }
  }

  // cross-wave reduce through LDS (4 rounds)
  for (int rnd = 0; rnd < 4; ++rnd) {
    if (w == rnd) {
#pragma unroll
      for (int ct = 0; ct < 13; ++ct) {
#pragma unroll
        for (int r = 0; r < 4; ++r) {
          int n = (lg << 2) + r;
          int c = (ct << 4) + lm;
          if (rnd == 0) outAcc[n][c] = oacc[ct][r];
          else outAcc[n][c] += oacc[ct][r];
        }
      }
    }
    __syncthreads();
  }

  // final write: 16 threads per c write 16 consecutive n (64B lines)
  {
    int lane16 = t & 15;
    int grp = t >> 4;
    for (int c = grp; c < 200; c += 16)
      out[(((size_t)(b * 200 + c)) << 12) + n0 + lane16] = outAcc[lane16][c];
  }
}

// ---------------------------------------------------------------------------
extern "C" void kernel_launch(void* const* d_in, const int* in_sizes, int n_in,
                              void* d_out, int out_size, void* d_ws,
                              size_t ws_size, hipStream_t stream) {
  const float* x  = (const float*)d_in[0];
  const float* tw = (const float*)d_in[1];
  const float* tb = (const float*)d_in[2];
  const float* pw = (const float*)d_in[3];
  const float* pb = (const float*)d_in[4];
  const float* gw = (const float*)d_in[5];
  const float* gb = (const float*)d_in[6];
  float* out = (float*)d_out;

  unsigned short* ws_us = (unsigned short*)d_ws;
  unsigned short* thd = ws_us;               // 8*4096*256     = 8,388,608 us
  unsigned short* phd = ws_us + 8388608;     // 8*1024*256     = 2,097,152
  unsigned short* gP  = ws_us + 10485760;    // 8*208*1024     = 1,703,936
  unsigned short* xTi = ws_us + 12189696;    // 8*70*70*128    = 5,017,600
  unsigned short* wTi = ws_us + 17207296;    // 49*448*128     = 2,809,856
  float* biasPad = (float*)(ws_us + 20017152);  // 448 f (~40.1 MB total)

  prep_x<<<560, 256, 0, stream>>>(x, (unsigned int*)xTi);
  prep_w<<<5488, 256, 0, stream>>>(tw, pw, gw, tb, pb, gb,
                                   (unsigned int*)wTi, biasPad);

  convmfma_kernel<<<dim3(64, 7), 512, 0, stream>>>(
      xTi, wTi, biasPad, (unsigned int*)thd, (unsigned int*)phd, gP);
  attn_kernel<<<2048, 256, 0, stream>>>(thd, phd, gP, out);
}

// Round 13
// 445.081 us; speedup vs baseline: 1.2274x; 1.1292x over previous
//
#include <hip/hip_runtime.h>
#include <cstdint>
#include <cstddef>

#define BATCH 8
#define CIN 64
#define HIN 70
#define HOUT 64
#define NPIX 4096
#define MPIX 1024

typedef __attribute__((ext_vector_type(8))) short short8;
typedef __attribute__((ext_vector_type(4))) float f32x4;
typedef __attribute__((ext_vector_type(4))) unsigned int uint4v;

__device__ __forceinline__ unsigned short f2bf_rne(float f) {
  unsigned int u = __builtin_bit_cast(unsigned int, f);
  unsigned int r = (u + 0x7FFFu + ((u >> 16) & 1u)) >> 16;
  return (unsigned short)r;
}

__device__ __forceinline__ unsigned int rot16(unsigned int u) {
  return (u >> 16) | (u << 16);
}

// ---------------------------------------------------------------------------
// prep_x: x -> xTi [8][70][70][128us] dual (hi,lo) pairs
//            + xTi_h [8][70][70][64us] hi-only (for single-bf16 g path)
// ---------------------------------------------------------------------------
__global__ __launch_bounds__(256) void prep_x(const float* __restrict__ x,
                                              unsigned int* __restrict__ xTi,
                                              unsigned int* __restrict__ xTi_h) {
  __shared__ float tile[64][71];
  const int blk = blockIdx.x;  // 0..559
  const int b = blk / 70;
  const int r = blk - b * 70;
  const int t = threadIdx.x;
  for (int i = t; i < 64 * 70; i += 256) {
    int ci = i / 70;
    int c = i - ci * 70;
    tile[ci][c] = x[(((size_t)(b * 64 + ci)) * 70 + r) * 70 + c];
  }
  __syncthreads();
  for (int i = t; i < 70 * 64; i += 256) {
    int c = i >> 6;
    int ci = i & 63;
    float a = tile[ci][c];
    unsigned short hi = f2bf_rne(a);
    float hif = __builtin_bit_cast(float, ((unsigned int)hi) << 16);
    unsigned short lo = f2bf_rne(a - hif);
    xTi[(((size_t)(b * 70 + r)) * 70 + c) * 64 + ci] =
        (unsigned int)hi | (((unsigned int)lo) << 16);
  }
  for (int i = t; i < 70 * 32; i += 256) {
    int c = i >> 5;
    int dwi = i & 31;
    unsigned int h0 = f2bf_rne(tile[2 * dwi][c]);
    unsigned int h1 = f2bf_rne(tile[2 * dwi + 1][c]);
    xTi_h[(((size_t)(b * 70 + r)) * 70 + c) * 32 + dwi] = h0 | (h1 << 16);
  }
}

// ---------------------------------------------------------------------------
// prep_w: wTi [49][448][64dw] dual pairs + biasPad[448]
//         wTi_s [49][192][32dw] hi-only (OC 256..447 = g[56..199] + pad)
// ---------------------------------------------------------------------------
__global__ __launch_bounds__(256) void prep_w(
    const float* __restrict__ tw, const float* __restrict__ pw,
    const float* __restrict__ gw,
    const float* __restrict__ tb, const float* __restrict__ pb,
    const float* __restrict__ gb,
    unsigned int* __restrict__ wTi, unsigned int* __restrict__ wTi_s,
    float* __restrict__ biasPad) {
  int gid = blockIdx.x * 256 + threadIdx.x;
  if (gid < 1404928) {  // 49*448*64 dual dwords
    if (gid < 448) {
      float bv = 0.0f;
      if (gid < 100) bv = tb[gid];
      else if (gid < 200) bv = pb[gid - 100];
      else if (gid < 400) bv = gb[gid - 200];
      biasPad[gid] = bv;
    }
    int ci = gid & 63;
    int OC = (gid >> 6) % 448;
    int s = gid / (448 * 64);
    float v = 0.0f;
    if (OC < 100) v = tw[((size_t)(OC * 64 + ci)) * 49 + s];
    else if (OC < 200) v = pw[((size_t)((OC - 100) * 64 + ci)) * 49 + s];
    else if (OC < 400) v = gw[((size_t)((OC - 200) * 64 + ci)) * 49 + s];
    unsigned short hi = f2bf_rne(v);
    float hif = __builtin_bit_cast(float, ((unsigned int)hi) << 16);
    unsigned short lo = f2bf_rne(v - hif);
    wTi[gid] = (unsigned int)hi | (((unsigned int)lo) << 16);
  } else if (gid < 1404928 + 301056) {  // 49*192*32 single dwords
    int g2 = gid - 1404928;
    int dwi = g2 & 31;
    int OCl = (g2 >> 5) % 192;
    int s = g2 / (192 * 32);
    int gc = 56 + OCl;  // g channel (oc = 256+OCl => gc = oc-200)
    float v0 = 0.0f, v1 = 0.0f;
    if (gc < 200) {
      v0 = gw[((size_t)(gc * 64 + 2 * dwi)) * 49 + s];
      v1 = gw[((size_t)(gc * 64 + 2 * dwi + 1)) * 49 + s];
    }
    wTi_s[g2] = (unsigned int)f2bf_rne(v0) |
                (((unsigned int)f2bf_rne(v1)) << 16);
  }
}

// ---------------------------------------------------------------------------
// convmfma v6: implicit-GEMM conv, 256-thr / 4-wave blocks, wave = 2 rows.
// DUAL=true  (oc 0..255): dual-bf16, 4 chunks of 16 ci, 2 MFMA per frag.
// DUAL=false (oc 256..447): single-bf16 hi-only, 2 chunks of 32 ci,
//            1 MFMA per frag (K=32 real channels), no rot16.
// Per slice per wave: 4 A + 8 B reads -> 64(dual)/32(single) MFMA.
// W through LDS pair-slots (2 slices/barrier), 2 units per thread.
// Epilogue: 2x2 pool fully intra-wave (row pair in regs, col pair shfl).
// ---------------------------------------------------------------------------
template <bool DUAL>
__global__ __launch_bounds__(256, 2) void convmfma_kernel(
    const unsigned short* __restrict__ xT,   // dual: [px][128] / single: [px][64]
    const unsigned short* __restrict__ wT,   // dual: [49][448][128] / [49][192][64]
    const float* __restrict__ biasPad,       // [448]
    unsigned int* __restrict__ thd_dw,       // [8][4096][128]
    unsigned int* __restrict__ phd_dw,       // [8][1024][128]
    unsigned short* __restrict__ gP) {       // [8][208][1024]
  __shared__ __align__(16) char smem[62720 + 16384];
  const int LDSW = 62720;
  const int NCH = DUAL ? 4 : 2;
  const int XS = DUAL ? 128 : 64;        // x px stride (ushorts)
  const int WOCS = DUAL ? 128 : 64;      // w oc stride (ushorts)
  const int WSTRIDE = DUAL ? 57344 : 12288;  // w slice stride (ushorts)

  const int gx = blockIdx.x;      // 0..63
  const int b = gx >> 3;
  const int ptile = gx & 7;
  const int oy0 = ptile * 8;
  const int oc0 = (DUAL ? 0 : 256) + (blockIdx.y << 6);
  const int oc0W = DUAL ? oc0 : (blockIdx.y << 6);

  const int t = threadIdx.x;      // 0..255
  const int wv = t >> 6;          // 0..3 : row-pair within block
  const int l = t & 63;
  const int lm = l & 15;
  const int lg = l >> 4;

  // W staging: 2 units per thread emulate the 512-thread mapping
  int wdstOff_[2];
  const unsigned short* wsrc_[2];
  const int keyA = ((lm >> 1) & 3) << 4;
  const int laneA = (lm << 6) + ((lg << 4) ^ keyA);

  f32x4 acc[4][2][4];  // [oc j][row rr][px f]
#pragma unroll
  for (int j = 0; j < 4; ++j)
#pragma unroll
    for (int rr = 0; rr < 2; ++rr)
#pragma unroll
      for (int f = 0; f < 4; ++f) acc[j][rr][f] = (f32x4)0.0f;

  for (int chunk = 0; chunk < NCH; ++chunk) {
    // ---- stage X chunk: [14][70] lines of 64B, 16B-quarter XOR swizzle
    for (int i = t; i < 3920; i += 256) {
      int idx70 = i >> 2;
      int s16 = i & 3;
      int rr = idx70 / 70;
      int cc = idx70 - rr * 70;
      const unsigned short* src =
          xT + ((size_t)((b * 70 + oy0 + rr) * 70 + cc)) * XS +
          (chunk << 5) + (s16 << 3);
      short8 v = *(const short8*)src;
      int dst = (idx70 << 6) + ((s16 << 4) ^ (((cc >> 1) & 3) << 4));
      *(short8*)(smem + dst) = v;
    }
    // ---- W pipeline prologue (pair-slots): slot0 <- pair0; wreg <- pair1
    short8 wreg[2];
#pragma unroll
    for (int u2 = 0; u2 < 2; ++u2) {
      int u = t + (u2 << 8);
      int sub = u >> 8;
      int oc_t = (u >> 2) & 63;
      int q = u & 3;
      wdstOff_[u2] =
          sub * 4096 + (oc_t << 6) + ((q << 4) ^ (((oc_t >> 1) & 3) << 4));
      wsrc_[u2] = wT + (size_t)(oc0W + oc_t) * WOCS + (chunk << 5) + (q << 3);
      wreg[u2] = *(const short8*)(wsrc_[u2] + (size_t)sub * WSTRIDE);
      *(short8*)(smem + LDSW + wdstOff_[u2]) = wreg[u2];
      wreg[u2] = *(const short8*)(wsrc_[u2] + (size_t)(2 + sub) * WSTRIDE);
    }
    __syncthreads();  // X staged + slot0 visible

    for (int p = 0; p < 25; ++p) {
      const char* slotBase = smem + LDSW + ((p & 1) << 13);
#pragma unroll
      for (int halfs = 0; halfs < 2; ++halfs) {
        const int s = 2 * p + halfs;
        if (s <= 48) {
          const int ky = s / 7;
          const int kx = s - ky * 7;
          // ---- A frags (weights)
          const char* wb = slotBase + (halfs << 12) + laneA;
          short8 aW[4], aS[4];
#pragma unroll
          for (int j = 0; j < 4; ++j) {
            aW[j] = *(const short8*)(wb + j * 1024);
            if (DUAL) {
              uint4v u = __builtin_bit_cast(uint4v, aW[j]);
              u.x = rot16(u.x); u.y = rot16(u.y);
              u.z = rot16(u.z); u.w = rot16(u.w);
              aS[j] = __builtin_bit_cast(short8, u);
            }
          }
          // ---- B frags (2 rows x 4 px-frags) + MFMA
          const int klx = kx + lm;
          const int key = ((klx >> 1) & 3) << 4;
#pragma unroll
          for (int rr = 0; rr < 2; ++rr) {
            const char* bbase =
                smem + ((2 * wv + rr + ky) * 70 + klx) * 64 + ((lg << 4) ^ key);
#pragma unroll
            for (int f = 0; f < 4; ++f) {
              short8 bf = *(const short8*)(bbase + f * 1024);
#pragma unroll
              for (int j = 0; j < 4; ++j) {
                acc[j][rr][f] = __builtin_amdgcn_mfma_f32_16x16x32_bf16(
                    aW[j], bf, acc[j][rr][f], 0, 0, 0);
                if (DUAL)
                  acc[j][rr][f] = __builtin_amdgcn_mfma_f32_16x16x32_bf16(
                      aS[j], bf, acc[j][rr][f], 0, 0, 0);
              }
            }
          }
        }
      }
      // ---- W pipeline: write pair p+1 into other slot; prefetch pair p+2
      if (p < 24) {
#pragma unroll
        for (int u2 = 0; u2 < 2; ++u2) {
          *(short8*)(smem + LDSW + (((p + 1) & 1) << 13) + wdstOff_[u2]) =
              wreg[u2];
          if (p < 23) {
            int sub = (t + (u2 << 8)) >> 8;
            int snext = 2 * (p + 2) + sub;
            if (snext > 48) snext = 48;
            wreg[u2] = *(const short8*)(wsrc_[u2] + (size_t)snext * WSTRIDE);
          }
        }
      }
      __syncthreads();  // one barrier per PAIR of slices
    }
  }

  // ---- epilogue: pool fully intra-wave; no LDS, no barriers ----
  float bia[4][4];
#pragma unroll
  for (int j = 0; j < 4; ++j)
#pragma unroll
    for (int r = 0; r < 4; ++r) bia[j][r] = biasPad[oc0 + j * 16 + lg * 4 + r];

  if (DUAL) {
    // theta full-res dual-bf16 + thd channel-pad zeros (dw 100..127)
#pragma unroll
    for (int j = 0; j < 4; ++j) {
#pragma unroll
      for (int rr = 0; rr < 2; ++rr) {
#pragma unroll
        for (int f = 0; f < 4; ++f) {
#pragma unroll
          for (int r = 0; r < 4; ++r) {
            int ch = oc0 + j * 16 + lg * 4 + r;
            if (ch < 128) {
              int n = (oy0 + 2 * wv + rr) * 64 + f * 16 + lm;
              unsigned int outw = 0u;
              if (ch < 100) {
                float v = acc[j][rr][f][r] + bia[j][r];
                unsigned short hi = f2bf_rne(v);
                float hif =
                    __builtin_bit_cast(float, ((unsigned int)hi) << 16);
                unsigned short lo = f2bf_rne(v - hif);
                outw = (unsigned int)hi | (((unsigned int)lo) << 16);
              }
              thd_dw[(((size_t)(b << 12) + n) << 7) + ch] = outw;
            }
          }
        }
      }
    }
  }

  // 2x2 maxpool: row pair in registers, col pair via shfl
#pragma unroll
  for (int j = 0; j < 4; ++j) {
#pragma unroll
    for (int f = 0; f < 4; ++f) {
#pragma unroll
      for (int r = 0; r < 4; ++r) {
        float v0 = acc[j][0][f][r] + bia[j][r];
        float v1 = acc[j][1][f][r] + bia[j][r];
        float vr = fmaxf(v0, v1);
        float vn = fmaxf(vr, __shfl_xor(vr, 1));
        if (!(lm & 1)) {
          int ch = oc0 + j * 16 + lg * 4 + r;
          int m = (((oy0 >> 1) + wv) << 5) + f * 8 + (lm >> 1);
          if (DUAL) {
            if (ch >= 100 && ch < 200) {
              int c = ch - 100;
              unsigned short hi = f2bf_rne(vn);
              float hif = __builtin_bit_cast(float, ((unsigned int)hi) << 16);
              unsigned short lo = f2bf_rne(vn - hif);
              phd_dw[(((size_t)(b << 10) + m) << 7) + c] =
                  (unsigned int)hi | (((unsigned int)lo) << 16);
            } else if (ch >= 200) {  // ch < 256 in dual tiles
              gP[((size_t)(b * 208 + (ch - 200)) << 10) + m] = f2bf_rne(vn);
              if (ch < 228)
                phd_dw[(((size_t)(b << 10) + m) << 7) + (ch - 100)] = 0u;
            }
          } else {
            int cg = ch - 200;  // 56..247
            if (cg < 208)
              gP[((size_t)(b * 208 + cg) << 10) + m] = f2bf_rne(vn);
          }
        }
      }
    }
  }
}

// ---------------------------------------------------------------------------
// attn v3 (unchanged from round 12, verified): swapped QK^T, register P.
// ---------------------------------------------------------------------------
__global__ __launch_bounds__(256) void attn_kernel(
    const unsigned short* __restrict__ thd,  // [8][4096][256]
    const unsigned short* __restrict__ phd,  // [8][1024][256]
    const unsigned short* __restrict__ gP,   // [8][208][1024]
    float* __restrict__ out) {               // [8][200][4096]
  __shared__ __align__(16) float outAcc[16][212];
  __shared__ float corrL[16][33];
  __shared__ float statsL[4][16][2];
  __shared__ float mFinL[16];
  __shared__ float invL[16];

  const int bx = blockIdx.x;   // 0..2047
  const int b = bx >> 8;
  const int n0 = (bx & 255) << 4;
  const int t = threadIdx.x;
  const int w = t >> 6;
  const int l = t & 63;
  const int lm = l & 15;
  const int lg = l >> 4;

  short8 aA[8], aS[8];
  {
    const unsigned short* ap =
        thd + (((size_t)(b << 12) + n0 + lm) << 8) + lg * 8;
#pragma unroll
    for (int kf = 0; kf < 8; ++kf) {
      short8 v = *(const short8*)(ap + kf * 32);
      aA[kf] = v;
      uint4v u = __builtin_bit_cast(uint4v, v);
      u.x = rot16(u.x); u.y = rot16(u.y); u.z = rot16(u.z); u.w = rot16(u.w);
      aS[kf] = __builtin_bit_cast(short8, u);
    }
  }

  float mRun = -3.0e38f, sRun = 0.0f;
  unsigned int Pr[8][4];

  const int src1 = ((lg & 1) << 5) + lm;
  const int src2 = src1 + 16;
  const bool hi2 = (lg >> 1) != 0;

#pragma unroll
  for (int step = 0; step < 8; ++step) {
    const int m0 = (w << 8) + (step << 5);
    f32x4 ac0 = (f32x4)0.f, ac1 = (f32x4)0.f;
    const unsigned short* bp0 =
        phd + (((size_t)(b << 10) + m0 + lm) << 8) + lg * 8;
    const unsigned short* bp1 = bp0 + (16 << 8);
#pragma unroll
    for (int kf = 0; kf < 8; ++kf) {
      short8 av0 = *(const short8*)(bp0 + kf * 32);
      short8 av1 = *(const short8*)(bp1 + kf * 32);
      ac0 = __builtin_amdgcn_mfma_f32_16x16x32_bf16(av0, aA[kf], ac0, 0, 0, 0);
      ac1 = __builtin_amdgcn_mfma_f32_16x16x32_bf16(av1, aA[kf], ac1, 0, 0, 0);
      ac0 = __builtin_amdgcn_mfma_f32_16x16x32_bf16(av0, aS[kf], ac0, 0, 0, 0);
      ac1 = __builtin_amdgcn_mfma_f32_16x16x32_bf16(av1, aS[kf], ac1, 0, 0, 0);
    }
    float tm = fmaxf(fmaxf(fmaxf(ac0[0], ac0[1]), fmaxf(ac0[2], ac0[3])),
                     fmaxf(fmaxf(ac1[0], ac1[1]), fmaxf(ac1[2], ac1[3])));
    tm = fmaxf(tm, __shfl_xor(tm, 16));
    tm = fmaxf(tm, __shfl_xor(tm, 32));
    float mNew = fmaxf(mRun, tm);
    float scale = __expf(mRun - mNew);
    float p0 = __expf(ac0[0] - mNew), p1 = __expf(ac0[1] - mNew);
    float p2 = __expf(ac0[2] - mNew), p3 = __expf(ac0[3] - mNew);
    float q0 = __expf(ac1[0] - mNew), q1 = __expf(ac1[1] - mNew);
    float q2 = __expf(ac1[2] - mNew), q3 = __expf(ac1[3] - mNew);
    float cs = ((p0 + p1) + (p2 + p3)) + ((q0 + q1) + (q2 + q3));
    cs += __shfl_xor(cs, 16);
    cs += __shfl_xor(cs, 32);
    mRun = mNew;
    sRun = sRun * scale + cs;
    if (l < 16) corrL[lm][(w << 3) + step] = mRun;
    unsigned int d0 = (unsigned int)f2bf_rne(p0) |
                      (((unsigned int)f2bf_rne(p1)) << 16);
    unsigned int d1 = (unsigned int)f2bf_rne(p2) |
                      (((unsigned int)f2bf_rne(p3)) << 16);
    unsigned int e0 = (unsigned int)f2bf_rne(q0) |
                      (((unsigned int)f2bf_rne(q1)) << 16);
    unsigned int e1 = (unsigned int)f2bf_rne(q2) |
                      (((unsigned int)f2bf_rne(q3)) << 16);
    unsigned int A0 = (unsigned int)__shfl((int)d0, src1);
    unsigned int A1 = (unsigned int)__shfl((int)d1, src1);
    unsigned int B0 = (unsigned int)__shfl((int)d0, src2);
    unsigned int B1 = (unsigned int)__shfl((int)d1, src2);
    unsigned int C0 = (unsigned int)__shfl((int)e0, src1);
    unsigned int C1 = (unsigned int)__shfl((int)e1, src1);
    unsigned int D0 = (unsigned int)__shfl((int)e0, src2);
    unsigned int D1 = (unsigned int)__shfl((int)e1, src2);
    Pr[step][0] = hi2 ? C0 : A0;
    Pr[step][1] = hi2 ? C1 : A1;
    Pr[step][2] = hi2 ? D0 : B0;
    Pr[step][3] = hi2 ? D1 : B1;
  }
  if (l < 16) {
    statsL[w][lm][0] = mRun;
    statsL[w][lm][1] = sRun;
  }
  __syncthreads();

  if (t < 16) {
    float mF = -3.0e38f;
#pragma unroll
    for (int qq = 0; qq < 4; ++qq) mF = fmaxf(mF, statsL[qq][t][0]);
    float sF = 0.0f;
#pragma unroll
    for (int qq = 0; qq < 4; ++qq)
      sF += statsL[qq][t][1] * __expf(statsL[qq][t][0] - mF);
    mFinL[t] = mF;
    invL[t] = 1.0f / sF;
  }
  __syncthreads();

  {
    int e = t * 2;
#pragma unroll
    for (int i = 0; i < 2; ++i) {
      int row = (e + i) >> 5;
      int col = (e + i) & 31;
      corrL[row][col] = __expf(corrL[row][col] - mFinL[row]) * invL[row];
    }
  }
  __syncthreads();

#pragma unroll
  for (int s = 0; s < 8; ++s) {
    float corr = corrL[lm][(w << 3) + s];
#pragma unroll
    for (int j = 0; j < 4; ++j) {
      unsigned int u = Pr[s][j];
      float lo = __builtin_bit_cast(float, u << 16);
      float hi = __builtin_bit_cast(float, u & 0xffff0000u);
      Pr[s][j] = (unsigned int)f2bf_rne(lo * corr) |
                 (((unsigned int)f2bf_rne(hi * corr)) << 16);
    }
  }

  f32x4 oacc[13];
#pragma unroll
  for (int i = 0; i < 13; ++i) oacc[i] = (f32x4)0.f;

#pragma unroll
  for (int s = 0; s < 8; ++s) {
    uint4v pu;
    pu.x = Pr[s][0]; pu.y = Pr[s][1]; pu.z = Pr[s][2]; pu.w = Pr[s][3];
    short8 pf = __builtin_bit_cast(short8, pu);
    const unsigned short* gbase =
        gP + ((size_t)(b * 208) << 10) + (w << 8) + (s << 5) + lg * 8;
#pragma unroll
    for (int ct = 0; ct < 13; ++ct) {
      int c = (ct << 4) + lm;
      short8 gv = *(const short8*)(gbase + ((size_t)c << 10));
      oacc[ct] = __builtin_amdgcn_mfma_f32_16x16x32_bf16(pf, gv, oacc[ct], 0, 0, 0);
    }
  }

  for (int rnd = 0; rnd < 4; ++rnd) {
    if (w == rnd) {
#pragma unroll
      for (int ct = 0; ct < 13; ++ct) {
#pragma unroll
        for (int r = 0; r < 4; ++r) {
          int n = (lg << 2) + r;
          int c = (ct << 4) + lm;
          if (rnd == 0) outAcc[n][c] = oacc[ct][r];
          else outAcc[n][c] += oacc[ct][r];
        }
      }
    }
    __syncthreads();
  }

  {
    int lane16 = t & 15;
    int grp = t >> 4;
    for (int c = grp; c < 200; c += 16)
      out[(((size_t)(b * 200 + c)) << 12) + n0 + lane16] = outAcc[lane16][c];
  }
}

// ---------------------------------------------------------------------------
extern "C" void kernel_launch(void* const* d_in, const int* in_sizes, int n_in,
                              void* d_out, int out_size, void* d_ws,
                              size_t ws_size, hipStream_t stream) {
  const float* x  = (const float*)d_in[0];
  const float* tw = (const float*)d_in[1];
  const float* tb = (const float*)d_in[2];
  const float* pw = (const float*)d_in[3];
  const float* pb = (const float*)d_in[4];
  const float* gw = (const float*)d_in[5];
  const float* gb = (const float*)d_in[6];
  float* out = (float*)d_out;

  unsigned short* ws_us = (unsigned short*)d_ws;
  unsigned short* thd   = ws_us;               //  8,388,608 us
  unsigned short* phd   = ws_us + 8388608;     //  2,097,152
  unsigned short* gP    = ws_us + 10485760;    //  1,703,936
  unsigned short* xTi   = ws_us + 12189696;    //  5,017,600
  unsigned short* wTi   = ws_us + 17207296;    //  2,809,856
  unsigned short* xTi_h = ws_us + 20017152;    //  2,508,800
  unsigned short* wTi_s = ws_us + 22525952;    //    602,112
  float* biasPad = (float*)(ws_us + 23128064); //  448 f  (~46.3 MB total)

  prep_x<<<560, 256, 0, stream>>>(x, (unsigned int*)xTi, (unsigned int*)xTi_h);
  prep_w<<<6664, 256, 0, stream>>>(tw, pw, gw, tb, pb, gb,
                                   (unsigned int*)wTi, (unsigned int*)wTi_s,
                                   biasPad);

  convmfma_kernel<true><<<dim3(64, 4), 256, 0, stream>>>(
      xTi, wTi, biasPad, (unsigned int*)thd, (unsigned int*)phd, gP);
  convmfma_kernel<false><<<dim3(64, 3), 256, 0, stream>>>(
      xTi_h, wTi_s, biasPad, (unsigned int*)thd, (unsigned int*)phd, gP);
  attn_kernel<<<2048, 256, 0, stream>>>(thd, phd, gP, out);
}